// Round 3
// baseline (1022.097 us; speedup 1.0000x reference)
//
#include <hip/hip_runtime.h>

// VariationalMPS: <M|H|M> / <M|M> via split-half environment sweeps.
// R3: single persistent kernel; 20 steps x (phaseA, grid-barrier, phaseB,
// grid-barrier) with device-scope atomic barriers; init/prep/dot/loss folded in.

#define D 128
#define W 8
#define NS 40
#define HALF 20
#define MSZ (D * 2 * D)      // 32768
#define HSZ (W * W * 2 * 2)  // 256
#define LSZ (D * W * D)      // 131072
#define NSZ (D * D)          // 16384
#define T2SZ (D * W * D * 2) // 262144
#define TNSZ (D * 2 * D)     // 32768

#define OFF_LL 0
#define OFF_LR (OFF_LL + LSZ)
#define OFF_NL (OFF_LR + LSZ)
#define OFF_NR (OFF_NL + NSZ)
#define OFF_T2L (OFF_NR + NSZ)  // envs live below this
#define OFF_T2R (OFF_T2L + T2SZ)
#define OFF_TNL (OFF_T2R + T2SZ)
#define OFF_TNR (OFF_TNL + TNSZ)
#define OFF_MREV (OFF_TNR + TNSZ)
#define OFF_HREV (OFF_MREV + HALF * MSZ)
#define OFF_PART (OFF_HREV + HALF * HSZ)   // 128 energy partials
#define OFF_PARTN (OFF_PART + 128)         // 128 norm partials
#define OFF_BAR (OFF_PARTN + 128)          // barrier counters (u32)

#define NBLK 192        // grid size; <= 256 CUs so all blocks co-resident
#define BAR_STRIDE 16   // 64B per counter, avoid false sharing
#define NBAR 48         // 42 used

// Zero the barrier counters (ws is poisoned 0xAA before every launch).
__global__ __launch_bounds__(256) void k_zero(float* ws) {
    unsigned* bar = (unsigned*)(ws + OFF_BAR);
    for (int i = threadIdx.x; i < NBAR * BAR_STRIDE; i += 256) bar[i] = 0u;
}

// Device-scope grid barrier: one fresh counter per barrier, no reset needed.
// Thread 0 release-adds (flushes this block's writes to device scope) and
// acquire-spins (invalidates caches); __syncthreads fans it out block-wide.
__device__ __forceinline__ void gbar(unsigned* bar, int bi) {
    __syncthreads();
    if (threadIdx.x == 0) {
        unsigned* c = bar + bi * BAR_STRIDE;
        __hip_atomic_fetch_add(c, 1u, __ATOMIC_RELEASE, __HIP_MEMORY_SCOPE_AGENT);
        while (__hip_atomic_load(c, __ATOMIC_ACQUIRE, __HIP_MEMORY_SCOPE_AGENT) < NBLK)
            __builtin_amdgcn_s_sleep(1);
    }
    __syncthreads();
}

__global__ __launch_bounds__(256) void k_sweep(const float* __restrict__ Min,
                                               const float* __restrict__ Hin,
                                               float* __restrict__ ws,
                                               float* __restrict__ out) {
    __shared__ float sm[7680];
    unsigned* bar = (unsigned*)(ws + OFF_BAR);
    const int bid = blockIdx.x;
    const int t = threadIdx.x;
    int bi = 0;

    // ---- phase 0: init envs + build reversed tensors ----
    for (int idx = bid * 256 + t; idx < OFF_T2L; idx += NBLK * 256) {
        float v = 0.f;
        if (idx == 0) v = 1.f;                         // L_left[0,0,0]
        else if (idx == OFF_LR + (W - 1) * D) v = 1.f; // L_right[0,W-1,0]
        else if (idx == OFF_NL) v = 1.f;               // N_left[0,0]
        else if (idx == OFF_NR) v = 1.f;               // N_right[0,0]
        ws[idx] = v;
    }
    // Mrev[k][p][i][a] = M[39-k][a][i][p]
    for (int idx = bid * 256 + t; idx < HALF * MSZ; idx += NBLK * 256) {
        int k = idx >> 15;
        int r = idx & (MSZ - 1);
        int p = r >> 8;
        int i = (r >> 7) & 1;
        int a = r & 127;
        ws[OFF_MREV + idx] = Min[(NS - 1 - k) * MSZ + a * 256 + i * 128 + p];
    }
    // Hrev[k][x][w][i][j] = H[39-k][w][x][i][j]
    for (int idx = bid * 256 + t; idx < HALF * HSZ; idx += NBLK * 256) {
        int k = idx >> 8;
        int r = idx & 255;
        int x = r >> 5, w = (r >> 2) & 7, i = (r >> 1) & 1, j = r & 1;
        ws[OFF_HREV + idx] = Hin[(NS - 1 - k) * HSZ + w * 32 + x * 4 + i * 2 + j];
    }
    gbar(bar, bi++);

    // ---- sweep ----
    for (int k = 0; k < HALF; ++k) {
        // ===== phase A =====
        if (bid < 128) {
            // energy: T1[w,b,i,p]=sum_a L[a,w,b] m[a,i,p], fuse h in regs,
            // write T2[p][x][b][j]
            int side = bid >> 6;
            int eb = bid & 63;
            int b0 = (eb & 7) * 16;
            int p0 = (eb >> 3) * 16;
            const float* Lsrc = ws + (side ? OFF_LR : OFF_LL);
            const float* m = side ? (ws + OFF_MREV + k * MSZ) : (Min + k * MSZ);
            const float* h = side ? (ws + OFF_HREV + k * HSZ) : (Hin + k * HSZ);
            float* T2 = ws + (side ? OFF_T2R : OFF_T2L);
            float* Ls = sm;          // [32a][16b][8w pad->12], row stride 200
            float* ms = sm + 6400;   // [32a][2i][16p]
            float* hs = sm + 7424;   // [16wi][16xj]
            hs[t] = h[((t >> 4) >> 1) * 32 + ((t & 15) >> 1) * 4 +
                      ((t >> 4) & 1) * 2 + (t & 1)];
            int b_l = t & 15, p_l = t >> 4;
            float acc[8][2];
#pragma unroll
            for (int w = 0; w < 8; ++w) { acc[w][0] = 0.f; acc[w][1] = 0.f; }
            for (int c = 0; c < 4; ++c) {
                int a0 = c * 32;
                __syncthreads();
#pragma unroll
                for (int u = 0; u < 4; ++u) {
                    int e = u * 256 + t;
                    int aa = e >> 5, w = (e >> 2) & 7, bq = e & 3;
                    const float4 v = *(const float4*)&Lsrc[(a0 + aa) * 1024 + w * 128 + b0 + bq * 4];
                    float* dst = &Ls[aa * 200 + bq * 48 + w];
                    dst[0] = v.x; dst[12] = v.y; dst[24] = v.z; dst[36] = v.w;
                }
                {
                    int aa = t >> 3, i = (t >> 2) & 1, pq = t & 3;
                    const float4 v = *(const float4*)&m[(a0 + aa) * 256 + i * 128 + p0 + pq * 4];
                    *(float4*)&ms[aa * 32 + i * 16 + pq * 4] = v;
                }
                __syncthreads();
#pragma unroll 4
                for (int aa = 0; aa < 32; ++aa) {
                    float4 l0 = *(float4*)&Ls[aa * 200 + b_l * 12];
                    float4 l1 = *(float4*)&Ls[aa * 200 + b_l * 12 + 4];
                    float m0 = ms[aa * 32 + p_l];
                    float m1 = ms[aa * 32 + 16 + p_l];
                    acc[0][0] += l0.x * m0; acc[0][1] += l0.x * m1;
                    acc[1][0] += l0.y * m0; acc[1][1] += l0.y * m1;
                    acc[2][0] += l0.z * m0; acc[2][1] += l0.z * m1;
                    acc[3][0] += l0.w * m0; acc[3][1] += l0.w * m1;
                    acc[4][0] += l1.x * m0; acc[4][1] += l1.x * m1;
                    acc[5][0] += l1.y * m0; acc[5][1] += l1.y * m1;
                    acc[6][0] += l1.z * m0; acc[6][1] += l1.z * m1;
                    acc[7][0] += l1.w * m0; acc[7][1] += l1.w * m1;
                }
            }
            float o[16];
#pragma unroll
            for (int xj = 0; xj < 16; ++xj) o[xj] = 0.f;
#pragma unroll
            for (int wi = 0; wi < 16; ++wi) {
                float tv = acc[wi >> 1][wi & 1];
                float4 h0 = *(float4*)&hs[wi * 16];
                float4 h1 = *(float4*)&hs[wi * 16 + 4];
                float4 h2 = *(float4*)&hs[wi * 16 + 8];
                float4 h3 = *(float4*)&hs[wi * 16 + 12];
                o[0] += tv * h0.x;  o[1] += tv * h0.y;  o[2] += tv * h0.z;  o[3] += tv * h0.w;
                o[4] += tv * h1.x;  o[5] += tv * h1.y;  o[6] += tv * h1.z;  o[7] += tv * h1.w;
                o[8] += tv * h2.x;  o[9] += tv * h2.y;  o[10] += tv * h2.z; o[11] += tv * h2.w;
                o[12] += tv * h3.x; o[13] += tv * h3.y; o[14] += tv * h3.z; o[15] += tv * h3.w;
            }
            int b = b0 + b_l, p = p0 + p_l;
            int base = p * 2048 + b * 2; // T2[p][x][b][j]
#pragma unroll
            for (int x = 0; x < 8; ++x) {
                float2 v; v.x = o[x * 2]; v.y = o[x * 2 + 1];
                *(float2*)&T2[base + x * 256] = v;
            }
        } else {
            // norm: Tn(b,i,p)=sum_a N[a,b] m[a,i,p], stored [p][b*2+i]
            int nb = bid - 128;
            int side = nb >> 5;
            int nn = nb & 31;
            int b0 = (nn & 3) * 32;
            int c0 = (nn >> 2) * 32;
            const float* Nsrc = ws + (side ? OFF_NR : OFF_NL);
            const float* m = side ? (ws + OFF_MREV + k * MSZ) : (Min + k * MSZ);
            float* Tn = ws + (side ? OFF_TNR : OFF_TNL);
            float* As = sm;         // [32][33]
            float* Bs = sm + 1056;  // [32][33]
            int ty = t >> 4, tx = t & 15;
            float a00 = 0, a01 = 0, a10 = 0, a11 = 0;
            for (int c = 0; c < 4; ++c) {
                int a0 = c * 32;
                __syncthreads();
                for (int u = 0; u < 4; ++u) {
                    int e = u * 256 + t;
                    int kk = e >> 5, col = e & 31;
                    As[kk * 33 + col] = Nsrc[(a0 + kk) * 128 + b0 + col];
                    Bs[kk * 33 + col] = m[(a0 + kk) * 256 + c0 + col];
                }
                __syncthreads();
                for (int kk = 0; kk < 32; ++kk) {
                    float av0 = As[kk * 33 + 2 * ty], av1 = As[kk * 33 + 2 * ty + 1];
                    float bv0 = Bs[kk * 33 + 2 * tx], bv1 = Bs[kk * 33 + 2 * tx + 1];
                    a00 += av0 * bv0;
                    a01 += av0 * bv1;
                    a10 += av1 * bv0;
                    a11 += av1 * bv1;
                }
            }
            int b_ = b0 + 2 * ty;
            int ip0 = c0 + 2 * tx, ip1 = ip0 + 1;
            int p0_ = ip0 & 127, i0 = ip0 >> 7;
            int p1_ = ip1 & 127, i1 = ip1 >> 7;
            Tn[p0_ * 256 + b_ * 2 + i0] = a00;
            Tn[p1_ * 256 + b_ * 2 + i1] = a01;
            Tn[p0_ * 256 + (b_ + 1) * 2 + i0] = a10;
            Tn[p1_ * 256 + (b_ + 1) * 2 + i1] = a11;
        }
        gbar(bar, bi++);

        // ===== phase B: C[r][c] = sum_k A[r][k] B[k][c] (32x64 tile, 2x4) =====
        if (bid < 144) {
            const float* A;
            const float* B;
            float* C;
            int r0, c0;
            if (bid < 128) {
                int side = bid >> 6;
                int eb = bid & 63;
                r0 = (eb & 31) * 32;
                c0 = (eb >> 5) * 64;
                A = ws + (side ? OFF_T2R : OFF_T2L);
                B = side ? (ws + OFF_MREV + k * MSZ) : (Min + k * MSZ);
                C = ws + (side ? OFF_LR : OFF_LL);
            } else {
                int nb = bid - 128;
                int side = nb >> 3;
                int nn = nb & 7;
                r0 = (nn & 3) * 32;
                c0 = (nn >> 2) * 64;
                A = ws + (side ? OFF_TNR : OFF_TNL);
                B = side ? (ws + OFF_MREV + k * MSZ) : (Min + k * MSZ);
                C = ws + (side ? OFF_NR : OFF_NL);
            }
            float* As = sm;         // [32k][32r pad->34]
            float* Bs = sm + 1088;  // [32k][64c pad->68]
            int ty = t >> 4, tx = t & 15;
            float a00 = 0, a01 = 0, a02 = 0, a03 = 0;
            float a10 = 0, a11 = 0, a12 = 0, a13 = 0;
            for (int c = 0; c < 8; ++c) {
                int k0 = c * 32;
                __syncthreads();
                {
                    int rr = t >> 3, kq = t & 7;
                    const float4 v = *(const float4*)&A[(r0 + rr) * 256 + k0 + kq * 4];
                    float* dst = &As[kq * 136 + rr];
                    dst[0] = v.x; dst[34] = v.y; dst[68] = v.z; dst[102] = v.w;
                }
#pragma unroll
                for (int u = 0; u < 2; ++u) {
                    int e = u * 256 + t;
                    int kk = e >> 4, cq = e & 15;
                    const float4 v = *(const float4*)&B[(k0 + kk) * 128 + c0 + cq * 4];
                    *(float4*)&Bs[kk * 68 + cq * 4] = v;
                }
                __syncthreads();
#pragma unroll 8
                for (int kk = 0; kk < 32; ++kk) {
                    float2 av = *(float2*)&As[kk * 34 + 2 * ty];
                    float4 bv = *(float4*)&Bs[kk * 68 + 4 * tx];
                    a00 += av.x * bv.x; a01 += av.x * bv.y; a02 += av.x * bv.z; a03 += av.x * bv.w;
                    a10 += av.y * bv.x; a11 += av.y * bv.y; a12 += av.y * bv.z; a13 += av.y * bv.w;
                }
            }
            int r = r0 + 2 * ty, cc = c0 + 4 * tx;
            float4 v0; v0.x = a00; v0.y = a01; v0.z = a02; v0.w = a03;
            float4 v1; v1.x = a10; v1.y = a11; v1.z = a12; v1.w = a13;
            *(float4*)&C[r * 128 + cc] = v0;
            *(float4*)&C[(r + 1) * 128 + cc] = v1;
        }
        gbar(bar, bi++);
    }

    // ---- dot partials: blocks 0..127 ----
    if (bid < 128) {
        float* se = sm;
        float* sn = sm + 256;
        const float* LL = ws + OFF_LL;
        const float* LR = ws + OFF_LR;
        float e = 0.f;
#pragma unroll
        for (int u = 0; u < 4; ++u) {
            int i = bid * 1024 + u * 256 + t;
            e += LL[i] * LR[i];
        }
        float n = 0.f;
        if (t < 128) {
            int i = bid * 128 + t;
            n = ws[OFF_NL + i] * ws[OFF_NR + i];
        }
        se[t] = e;
        sn[t] = n;
        __syncthreads();
        for (int s = 128; s > 0; s >>= 1) {
            if (t < s) { se[t] += se[t + s]; sn[t] += sn[t + s]; }
            __syncthreads();
        }
        if (t == 0) {
            ws[OFF_PART + bid] = se[0];
            ws[OFF_PARTN + bid] = sn[0];
        }
    }
    gbar(bar, bi++);

    // ---- final reduce + loss: block 0 ----
    if (bid == 0) {
        float* se = sm;
        float* sn = sm + 128;
        if (t < 128) {
            se[t] = ws[OFF_PART + t];
            sn[t] = ws[OFF_PARTN + t];
        }
        __syncthreads();
        for (int s = 64; s > 0; s >>= 1) {
            if (t < s) { se[t] += se[t + s]; sn[t] += sn[t + s]; }
            __syncthreads();
        }
        if (t == 0) {
            float E = se[0], Nm = sn[0];
            out[0] = E;
            out[1] = Nm;
            out[2] = E / Nm;
            out[3] = fmaxf(Nm - 10000.0f, 0.0f);
        }
    }
}

extern "C" void kernel_launch(void* const* d_in, const int* in_sizes, int n_in,
                              void* d_out, int out_size, void* d_ws, size_t ws_size,
                              hipStream_t stream) {
    const float* Min = (const float*)d_in[0];
    const float* Hin = (const float*)d_in[1];
    float* ws = (float*)d_ws;
    float* out = (float*)d_out;
    (void)in_sizes; (void)n_in; (void)out_size; (void)ws_size;

    k_zero<<<dim3(1), dim3(256), 0, stream>>>(ws);
    k_sweep<<<dim3(NBLK), dim3(256), 0, stream>>>(Min, Hin, ws, out);
}

// Round 4
// 731.583 us; speedup vs baseline: 1.3971x; 1.3971x over previous
//
#include <hip/hip_runtime.h>

// VariationalMPS: <M|H|M> / <M|M> via split-half environment sweeps.
// R4: persistent kernel with FIXED grid barriers: relaxed polling + single
// acquire fence (no per-poll L2 invalidate), 8-leaf arrival spreading, and
// 4 independent per-chain barriers (E-L 64, E-R 64, N-L 32, N-R 32 blocks).

#define D 128
#define W 8
#define NS 40
#define HALF 20
#define MSZ (D * 2 * D)      // 32768
#define HSZ (W * W * 2 * 2)  // 256
#define LSZ (D * W * D)      // 131072
#define NSZ (D * D)          // 16384
#define T2SZ (D * W * D * 2) // 262144
#define TNSZ (D * 2 * D)     // 32768

#define OFF_LL 0
#define OFF_LR (OFF_LL + LSZ)
#define OFF_NL (OFF_LR + LSZ)
#define OFF_NR (OFF_NL + NSZ)
#define OFF_T2L (OFF_NR + NSZ)
#define OFF_T2R (OFF_T2L + T2SZ)
#define OFF_TNL (OFF_T2R + T2SZ)
#define OFF_TNR (OFF_TNL + TNSZ)
#define OFF_MREV (OFF_TNR + TNSZ)
#define OFF_HREV (OFF_MREV + HALF * MSZ)
#define OFF_PART (OFF_HREV + HALF * HSZ)
#define OFF_PARTN (OFF_PART + 128)
#define OFF_BAR (OFF_PARTN + 128)

#define NBLK 192
#define NLEAF 8
#define LEAF_STRIDE 16
#define SLOT_U32 (NLEAF * LEAF_STRIDE)
#define SLOTS 44
#define REGION_U32 (SLOTS * SLOT_U32)
#define NREGION 5
#define BAR_TOTAL_U32 (NREGION * REGION_U32)

__global__ __launch_bounds__(256) void k_zero(float* ws) {
    unsigned* bar = (unsigned*)(ws + OFF_BAR);
    int idx = blockIdx.x * 256 + threadIdx.x;
    if (idx < BAR_TOTAL_U32) bar[idx] = 0u;
}

// Arrival: release RMW spread over 8 leaf lines. Wait: 8 lanes poll one leaf
// each with RELAXED loads (no per-poll cache maintenance). One agent-acquire
// fence after exit, then block barrier.
__device__ __forceinline__ void bar_sync(unsigned* region, int slot, int leaf,
                                         int expect_per_leaf) {
    unsigned* s = region + slot * SLOT_U32;
    __syncthreads();
    if (threadIdx.x == 0) {
        __hip_atomic_fetch_add(s + leaf * LEAF_STRIDE, 1u, __ATOMIC_RELEASE,
                               __HIP_MEMORY_SCOPE_AGENT);
    }
    if (threadIdx.x < NLEAF) {
        while ((int)__hip_atomic_load(s + threadIdx.x * LEAF_STRIDE,
                                      __ATOMIC_RELAXED,
                                      __HIP_MEMORY_SCOPE_AGENT) < expect_per_leaf)
            __builtin_amdgcn_s_sleep(2);
    }
    if (threadIdx.x == 0) __builtin_amdgcn_fence(__ATOMIC_ACQUIRE, "agent");
    __syncthreads();
}

__global__ __launch_bounds__(256) void k_sweep(const float* __restrict__ Min,
                                               const float* __restrict__ Hin,
                                               float* __restrict__ ws,
                                               float* __restrict__ out) {
    __shared__ float sm[7680];
    unsigned* bar = (unsigned*)(ws + OFF_BAR);
    const int bid = blockIdx.x;
    const int t = threadIdx.x;

    int chain, lid, cexp;
    if (bid < 64)       { chain = 0; lid = bid;       cexp = 8; }
    else if (bid < 128) { chain = 1; lid = bid - 64;  cexp = 8; }
    else if (bid < 160) { chain = 2; lid = bid - 128; cexp = 4; }
    else                { chain = 3; lid = bid - 160; cexp = 4; }
    const int side = (chain == 1 || chain == 3);
    const int leaf = lid & (NLEAF - 1);
    unsigned* creg = bar + chain * REGION_U32;
    unsigned* greg = bar + 4 * REGION_U32;
    const int gleaf = bid & (NLEAF - 1);

    // ---- init envs + reversed tensors ----
    for (int idx = bid * 256 + t; idx < OFF_T2L; idx += NBLK * 256) {
        float v = 0.f;
        if (idx == 0) v = 1.f;
        else if (idx == OFF_LR + (W - 1) * D) v = 1.f;
        else if (idx == OFF_NL) v = 1.f;
        else if (idx == OFF_NR) v = 1.f;
        ws[idx] = v;
    }
    for (int idx = bid * 256 + t; idx < HALF * MSZ; idx += NBLK * 256) {
        int k = idx >> 15;
        int r = idx & (MSZ - 1);
        int p = r >> 8;
        int i = (r >> 7) & 1;
        int a = r & 127;
        ws[OFF_MREV + idx] = Min[(NS - 1 - k) * MSZ + a * 256 + i * 128 + p];
    }
    for (int idx = bid * 256 + t; idx < HALF * HSZ; idx += NBLK * 256) {
        int k = idx >> 8;
        int r = idx & 255;
        int x = r >> 5, w = (r >> 2) & 7, i = (r >> 1) & 1, j = r & 1;
        ws[OFF_HREV + idx] = Hin[(NS - 1 - k) * HSZ + w * 32 + x * 4 + i * 2 + j];
    }
    bar_sync(greg, 0, gleaf, NBLK / NLEAF);

    // ---- sweep ----
    for (int k = 0; k < HALF; ++k) {
        const float* m = side ? (ws + OFF_MREV + k * MSZ) : (Min + k * MSZ);
        // ===== phase A =====
        if (chain < 2) {
            int b0 = (lid & 7) * 16;
            int p0 = (lid >> 3) * 16;
            const float* Lsrc = ws + (side ? OFF_LR : OFF_LL);
            const float* h = side ? (ws + OFF_HREV + k * HSZ) : (Hin + k * HSZ);
            float* T2 = ws + (side ? OFF_T2R : OFF_T2L);
            float* Ls = sm;          // [32a][16b][8w pad->12], row stride 200
            float* ms = sm + 6400;   // [32a][2i][16p]
            float* hs = sm + 7424;   // [16wi][16xj]
            hs[t] = h[((t >> 4) >> 1) * 32 + ((t & 15) >> 1) * 4 +
                      ((t >> 4) & 1) * 2 + (t & 1)];
            int b_l = t & 15, p_l = t >> 4;
            float acc[8][2];
#pragma unroll
            for (int w = 0; w < 8; ++w) { acc[w][0] = 0.f; acc[w][1] = 0.f; }
            for (int c = 0; c < 4; ++c) {
                int a0 = c * 32;
                __syncthreads();
#pragma unroll
                for (int u = 0; u < 4; ++u) {
                    int e = u * 256 + t;
                    int aa = e >> 5, w = (e >> 2) & 7, bq = e & 3;
                    const float4 v = *(const float4*)&Lsrc[(a0 + aa) * 1024 + w * 128 + b0 + bq * 4];
                    float* dst = &Ls[aa * 200 + bq * 48 + w];
                    dst[0] = v.x; dst[12] = v.y; dst[24] = v.z; dst[36] = v.w;
                }
                {
                    int aa = t >> 3, i = (t >> 2) & 1, pq = t & 3;
                    const float4 v = *(const float4*)&m[(a0 + aa) * 256 + i * 128 + p0 + pq * 4];
                    *(float4*)&ms[aa * 32 + i * 16 + pq * 4] = v;
                }
                __syncthreads();
#pragma unroll 4
                for (int aa = 0; aa < 32; ++aa) {
                    float4 l0 = *(float4*)&Ls[aa * 200 + b_l * 12];
                    float4 l1 = *(float4*)&Ls[aa * 200 + b_l * 12 + 4];
                    float m0 = ms[aa * 32 + p_l];
                    float m1 = ms[aa * 32 + 16 + p_l];
                    acc[0][0] += l0.x * m0; acc[0][1] += l0.x * m1;
                    acc[1][0] += l0.y * m0; acc[1][1] += l0.y * m1;
                    acc[2][0] += l0.z * m0; acc[2][1] += l0.z * m1;
                    acc[3][0] += l0.w * m0; acc[3][1] += l0.w * m1;
                    acc[4][0] += l1.x * m0; acc[4][1] += l1.x * m1;
                    acc[5][0] += l1.y * m0; acc[5][1] += l1.y * m1;
                    acc[6][0] += l1.z * m0; acc[6][1] += l1.z * m1;
                    acc[7][0] += l1.w * m0; acc[7][1] += l1.w * m1;
                }
            }
            float o[16];
#pragma unroll
            for (int xj = 0; xj < 16; ++xj) o[xj] = 0.f;
#pragma unroll
            for (int wi = 0; wi < 16; ++wi) {
                float tv = acc[wi >> 1][wi & 1];
                float4 h0 = *(float4*)&hs[wi * 16];
                float4 h1 = *(float4*)&hs[wi * 16 + 4];
                float4 h2 = *(float4*)&hs[wi * 16 + 8];
                float4 h3 = *(float4*)&hs[wi * 16 + 12];
                o[0] += tv * h0.x;  o[1] += tv * h0.y;  o[2] += tv * h0.z;  o[3] += tv * h0.w;
                o[4] += tv * h1.x;  o[5] += tv * h1.y;  o[6] += tv * h1.z;  o[7] += tv * h1.w;
                o[8] += tv * h2.x;  o[9] += tv * h2.y;  o[10] += tv * h2.z; o[11] += tv * h2.w;
                o[12] += tv * h3.x; o[13] += tv * h3.y; o[14] += tv * h3.z; o[15] += tv * h3.w;
            }
            int b = b0 + b_l, p = p0 + p_l;
            int base = p * 2048 + b * 2; // T2[p][x][b][j]
#pragma unroll
            for (int x = 0; x < 8; ++x) {
                float2 v; v.x = o[x * 2]; v.y = o[x * 2 + 1];
                *(float2*)&T2[base + x * 256] = v;
            }
        } else {
            int b0 = (lid & 3) * 32;
            int c0 = (lid >> 2) * 32;
            const float* Nsrc = ws + (side ? OFF_NR : OFF_NL);
            float* Tn = ws + (side ? OFF_TNR : OFF_TNL);
            float* As = sm;         // [32][33]
            float* Bs = sm + 1056;  // [32][33]
            int ty = t >> 4, tx = t & 15;
            float a00 = 0, a01 = 0, a10 = 0, a11 = 0;
            for (int c = 0; c < 4; ++c) {
                int a0 = c * 32;
                __syncthreads();
                for (int u = 0; u < 4; ++u) {
                    int e = u * 256 + t;
                    int kk = e >> 5, col = e & 31;
                    As[kk * 33 + col] = Nsrc[(a0 + kk) * 128 + b0 + col];
                    Bs[kk * 33 + col] = m[(a0 + kk) * 256 + c0 + col];
                }
                __syncthreads();
                for (int kk = 0; kk < 32; ++kk) {
                    float av0 = As[kk * 33 + 2 * ty], av1 = As[kk * 33 + 2 * ty + 1];
                    float bv0 = Bs[kk * 33 + 2 * tx], bv1 = Bs[kk * 33 + 2 * tx + 1];
                    a00 += av0 * bv0;
                    a01 += av0 * bv1;
                    a10 += av1 * bv0;
                    a11 += av1 * bv1;
                }
            }
            int b_ = b0 + 2 * ty;
            int ip0 = c0 + 2 * tx, ip1 = ip0 + 1;
            int p0_ = ip0 & 127, i0 = ip0 >> 7;
            int p1_ = ip1 & 127, i1 = ip1 >> 7;
            Tn[p0_ * 256 + b_ * 2 + i0] = a00;
            Tn[p1_ * 256 + b_ * 2 + i1] = a01;
            Tn[p0_ * 256 + (b_ + 1) * 2 + i0] = a10;
            Tn[p1_ * 256 + (b_ + 1) * 2 + i1] = a11;
        }
        bar_sync(creg, 2 * k, leaf, cexp);

        // ===== phase B =====
        if (chain < 2) {
            // energy: C=L' (1024x128) = T2 (1024x256) x m (256x128); 32x64 tile
            int r0 = (lid & 31) * 32;
            int c0 = (lid >> 5) * 64;
            const float* A = ws + (side ? OFF_T2R : OFF_T2L);
            float* C = ws + (side ? OFF_LR : OFF_LL);
            float* As = sm;         // [32k][32r pad->34]
            float* Bs = sm + 1088;  // [32k][64c pad->68]
            int ty = t >> 4, tx = t & 15;
            float a00 = 0, a01 = 0, a02 = 0, a03 = 0;
            float a10 = 0, a11 = 0, a12 = 0, a13 = 0;
            for (int c = 0; c < 8; ++c) {
                int k0 = c * 32;
                __syncthreads();
                {
                    int rr = t >> 3, kq = t & 7;
                    const float4 v = *(const float4*)&A[(r0 + rr) * 256 + k0 + kq * 4];
                    float* dst = &As[kq * 136 + rr];
                    dst[0] = v.x; dst[34] = v.y; dst[68] = v.z; dst[102] = v.w;
                }
#pragma unroll
                for (int u = 0; u < 2; ++u) {
                    int e = u * 256 + t;
                    int kk = e >> 4, cq = e & 15;
                    const float4 v = *(const float4*)&m[(k0 + kk) * 128 + c0 + cq * 4];
                    *(float4*)&Bs[kk * 68 + cq * 4] = v;
                }
                __syncthreads();
#pragma unroll 8
                for (int kk = 0; kk < 32; ++kk) {
                    float2 av = *(float2*)&As[kk * 34 + 2 * ty];
                    float4 bv = *(float4*)&Bs[kk * 68 + 4 * tx];
                    a00 += av.x * bv.x; a01 += av.x * bv.y; a02 += av.x * bv.z; a03 += av.x * bv.w;
                    a10 += av.y * bv.x; a11 += av.y * bv.y; a12 += av.y * bv.z; a13 += av.y * bv.w;
                }
            }
            int r = r0 + 2 * ty, cc = c0 + 4 * tx;
            float4 v0; v0.x = a00; v0.y = a01; v0.z = a02; v0.w = a03;
            float4 v1; v1.x = a10; v1.y = a11; v1.z = a12; v1.w = a13;
            *(float4*)&C[r * 128 + cc] = v0;
            *(float4*)&C[(r + 1) * 128 + cc] = v1;
        } else {
            // norm: C=N' (128x128) = Tn (128x256) x m (256x128); 16x32 tile
            int r0 = (lid & 7) * 16;
            int c0 = (lid >> 3) * 32;
            const float* A = ws + (side ? OFF_TNR : OFF_TNL);
            float* C = ws + (side ? OFF_NR : OFF_NL);
            float* As = sm;         // [32k][16r pad->17]
            float* Bs = sm + 544;   // [32k][32c pad->34]
            int ty = t >> 4, tx = t & 15;
            float a0 = 0, a1 = 0;
            for (int c = 0; c < 8; ++c) {
                int k0 = c * 32;
                __syncthreads();
                if (t < 128) {
                    int rr = t >> 3, kq = t & 7;
                    const float4 v = *(const float4*)&A[(r0 + rr) * 256 + k0 + kq * 4];
                    float* dst = &As[kq * 68 + rr];
                    dst[0] = v.x; dst[17] = v.y; dst[34] = v.z; dst[51] = v.w;
                }
                {
                    int kk = t >> 3, cq = t & 7;
                    const float4 v = *(const float4*)&m[(k0 + kk) * 128 + c0 + cq * 4];
                    *(float4*)&Bs[kk * 34 + cq * 4] = v;
                }
                __syncthreads();
                for (int kk = 0; kk < 32; ++kk) {
                    float av = As[kk * 17 + ty];
                    float2 bv = *(float2*)&Bs[kk * 34 + 2 * tx];
                    a0 += av * bv.x;
                    a1 += av * bv.y;
                }
            }
            float2 v; v.x = a0; v.y = a1;
            *(float2*)&C[(r0 + ty) * 128 + c0 + 2 * tx] = v;
        }
        bar_sync(creg, 2 * k + 1, leaf, cexp);
    }

    bar_sync(greg, 1, gleaf, NBLK / NLEAF);

    // ---- dot partials: blocks 0..127 ----
    if (bid < 128) {
        float* se = sm;
        float* sn = sm + 256;
        const float* LL = ws + OFF_LL;
        const float* LR = ws + OFF_LR;
        float e = 0.f;
#pragma unroll
        for (int u = 0; u < 4; ++u) {
            int i = bid * 1024 + u * 256 + t;
            e += LL[i] * LR[i];
        }
        float n = 0.f;
        if (t < 128) {
            int i = bid * 128 + t;
            n = ws[OFF_NL + i] * ws[OFF_NR + i];
        }
        se[t] = e;
        sn[t] = n;
        __syncthreads();
        for (int s = 128; s > 0; s >>= 1) {
            if (t < s) { se[t] += se[t + s]; sn[t] += sn[t + s]; }
            __syncthreads();
        }
        if (t == 0) {
            ws[OFF_PART + bid] = se[0];
            ws[OFF_PARTN + bid] = sn[0];
        }
    }
    bar_sync(greg, 2, gleaf, NBLK / NLEAF);

    // ---- final reduce + loss ----
    if (bid == 0) {
        float* se = sm;
        float* sn = sm + 128;
        if (t < 128) {
            se[t] = ws[OFF_PART + t];
            sn[t] = ws[OFF_PARTN + t];
        }
        __syncthreads();
        for (int s = 64; s > 0; s >>= 1) {
            if (t < s) { se[t] += se[t + s]; sn[t] += sn[t + s]; }
            __syncthreads();
        }
        if (t == 0) {
            float E = se[0], Nm = sn[0];
            out[0] = E;
            out[1] = Nm;
            out[2] = E / Nm;
            out[3] = fmaxf(Nm - 10000.0f, 0.0f);
        }
    }
}

extern "C" void kernel_launch(void* const* d_in, const int* in_sizes, int n_in,
                              void* d_out, int out_size, void* d_ws, size_t ws_size,
                              hipStream_t stream) {
    const float* Min = (const float*)d_in[0];
    const float* Hin = (const float*)d_in[1];
    float* ws = (float*)d_ws;
    float* out = (float*)d_out;
    (void)in_sizes; (void)n_in; (void)out_size; (void)ws_size;

    k_zero<<<dim3((BAR_TOTAL_U32 + 255) / 256), dim3(256), 0, stream>>>(ws);
    k_sweep<<<dim3(NBLK), dim3(256), 0, stream>>>(Min, Hin, ws, out);
}